// Round 3
// baseline (455.947 us; speedup 1.0000x reference)
//
#include <hip/hip_runtime.h>

#define NN 50000
#define NE 800000
#define CAP 64          // padded CSR slots per node (max deg_in ~40 for Poisson(16))

// ---- bucketed build parameters ----
#define NPB 128         // nodes per bucket (dst >> 7)
#define NBKT 391        // ceil(NN / NPB)
#define NBKT_PAD 512
#define BCAP 3072       // partition slots per bucket (mean 2048, sigma ~45 -> 22 sigma margin)
#define CHUNK 4096      // edges per partition block

typedef unsigned short u16;
typedef unsigned int u32;
typedef __attribute__((ext_vector_type(8))) short bf8_t;   // 8 x bf16 (4 VGPRs)
typedef __attribute__((ext_vector_type(4))) float f4_t;    // 4 x f32 acc

__device__ __forceinline__ u16 f2b(float f) {              // RNE fp32 -> bf16
    unsigned u = __float_as_uint(f);
    unsigned r = u + 0x7FFF + ((u >> 16) & 1);
    return (u16)(r >> 16);
}

// ---------------- streaming edge-feature aggregation (replaces gather_e2_k) -------------
// efa[d] += ef[e]  via fire-and-forget global f32 atomics. Reads are SEQUENTIAL in eid
// (full-BW stream) instead of a CSR-ordered random permutation of a 102 MB array
// (which was latency-bound at 1.7 TB/s). efa (6.4 MB) stays cache-resident.
// fp32 add order is nondeterministic -- same as the pre-existing CSR-slot race order.
__global__ __launch_bounds__(256) void edge_agg_k(
    const float* __restrict__ ef, const int* __restrict__ dst,
    float* __restrict__ efa, int E) {
    const int lane = threadIdx.x & 63;
    const int wv = blockIdx.x * 4 + (threadIdx.x >> 6);
    const int e0 = wv * 32;                 // 32 contiguous edges per wave
    if (e0 >= E) return;
    const int off = lane & 31;
    const int half = lane >> 5;

    int myd = 0;
    if (lane < 32) myd = dst[e0 + lane];    // 32 dsts staged in lanes 0..31

    float v[16];
#pragma unroll
    for (int j = 0; j < 16; ++j)            // 16 x 256B coalesced loads, all in flight
        v[j] = ef[(size_t)(e0 + 2 * j + half) * 32 + off];
#pragma unroll
    for (int j = 0; j < 16; ++j) {
        int d = __shfl(myd, 2 * j + half);
        atomicAdd(efa + (size_t)d * 32 + off, v[j]);   // no-return atomic: no stall
    }
}

// ---------------- pass A: LDS-staged partition of edges into dst-buckets ----------------
// Packs {dst:16 | src:16} into u32; copy-out is bucket-contiguous bursts so HBM lines
// fill fully. Also builds deg_out histogram.
__global__ __launch_bounds__(256) void partition_k(
    const int* __restrict__ src, const int* __restrict__ dst,
    int* __restrict__ deg_out, int* __restrict__ bktc,
    u32* __restrict__ part, int E) {
    __shared__ unsigned cnt[NBKT_PAD];
    __shared__ unsigned base[NBKT_PAD];
    __shared__ unsigned cur[NBKT_PAD];
    __shared__ unsigned gbase[NBKT_PAD];
    __shared__ unsigned wtot[4];
    __shared__ u32 staged[CHUNK];

    const int tid = threadIdx.x;
    const int lane = tid & 63;
    const int wid = tid >> 6;
    const int e0 = blockIdx.x * CHUNK;
    const int n = min(CHUNK, E - e0);

    for (int i = tid; i < NBKT_PAD; i += 256) cnt[i] = 0;
    __syncthreads();

    // histogram buckets for this chunk
    for (int i = tid; i < n; i += 256) {
        int d = dst[e0 + i];
        atomicAdd(&cnt[d >> 7], 1u);
    }
    __syncthreads();

    // exclusive scan cnt[0..511] -> base (pairs per thread + shfl wave scan)
    {
        unsigned a = cnt[2 * tid];
        unsigned b = cnt[2 * tid + 1];
        unsigned ps = a + b;
        unsigned inc = ps;
#pragma unroll
        for (int d = 1; d < 64; d <<= 1) {
            unsigned v = __shfl_up(inc, d);
            if (lane >= d) inc += v;
        }
        if (lane == 63) wtot[wid] = inc;
        __syncthreads();
        unsigned wb = 0;
#pragma unroll
        for (int k = 0; k < 4; ++k) wb += (k < wid) ? wtot[k] : 0;
        unsigned eb = wb + inc - ps;        // exclusive base of pair slot 2*tid
        base[2 * tid] = eb;
        base[2 * tid + 1] = eb + a;
        cur[2 * tid] = eb;
        cur[2 * tid + 1] = eb + a;
    }
    __syncthreads();

    // scatter into LDS staging, bucket-sorted; deg_out histogram on the side
    for (int i = tid; i < n; i += 256) {
        int e = e0 + i;
        int d = dst[e];
        int s = src[e];
        atomicAdd(deg_out + s, 1);
        unsigned p = atomicAdd(&cur[d >> 7], 1u);
        staged[p] = ((u32)d << 16) | (u32)s;
    }
    __syncthreads();

    // reserve global space per bucket
    for (int b = tid; b < NBKT; b += 256) {
        unsigned c = cur[b] - base[b];
        if (c) gbase[b] = (unsigned)atomicAdd(&bktc[b], (int)c);
    }
    __syncthreads();

    // copy out: consecutive i within a bucket -> consecutive global slots (bursts)
    for (int i = tid; i < n; i += 256) {
        u32 v = staged[i];
        int b = (int)(v >> 23);             // (dst >> 7)
        unsigned idx = gbase[b] + ((unsigned)i - base[b]);
        if (idx < BCAP) part[(size_t)b * BCAP + idx] = v;
    }
}

// ---------------- pass B: per-bucket CSR fill (32KB window, L2-resident) ----------------
// One block per bucket; LDS cursors give final deg_in for free.
__global__ __launch_bounds__(256) void fill_k(
    const u32* __restrict__ part, const int* __restrict__ bktc,
    int* __restrict__ csr, int* __restrict__ din, int n) {
    __shared__ unsigned cur[NPB];
    const int tid = threadIdx.x;
    const int b = blockIdx.x;
    const int node0 = b << 7;
    if (tid < NPB) cur[tid] = 0;
    __syncthreads();

    const int cnt = min(bktc[b], BCAP);
    const u32* p = part + (size_t)b * BCAP;
    for (int i = tid; i < cnt; i += 256) {
        u32 v = p[i];
        int s = (int)(v & 0xffffu);
        int d = (int)(v >> 16);
        unsigned q = atomicAdd(&cur[d & (NPB - 1)], 1u);
        if (q < CAP) csr[((size_t)d << 6) + q] = s;
    }
    __syncthreads();
    int node = node0 + tid;
    if (tid < NPB && node < n) din[node] = (int)cur[tid];
}

__global__ void make_inv_k(const int* __restrict__ deg_in, const int* __restrict__ deg_out,
                           float* __restrict__ inv_in, float* __restrict__ inv_out,
                           float* __restrict__ inv_mean, float* __restrict__ bcoef, int n) {
    int i = blockIdx.x * 256 + threadIdx.x;
    if (i < n) {
        int d_in = deg_in[i];
        float di = fmaxf((float)d_in, 1.0f);
        float dq = fmaxf((float)deg_out[i], 1.0f);
        inv_in[i]   = 1.0f / sqrtf(di);
        inv_out[i]  = 1.0f / sqrtf(dq);
        inv_mean[i] = 1.0f / di;
        bcoef[i]    = (d_in > 0) ? 1.0f : 0.0f;
    }
}

// ---------------- bf16 gather, wave-per-node, 16-deep batches ----------------
// agg[d] = bf16( inv_in[d] * sum_e h[src_e] );  h pre-scaled by inv_out.
template <int D, int LPT>
__global__ __launch_bounds__(256) void gather_b2_k(
    const u16* __restrict__ h, const int* __restrict__ csr,
    const int* __restrict__ deg, const float* __restrict__ inv_in,
    u16* __restrict__ agg) {
    constexpr int ACT = D / LPT;
    constexpr int NW = LPT / 2;          // uints per lane-load
    const int lane = threadIdx.x & 63;
    const int node = __builtin_amdgcn_readfirstlane(blockIdx.x * 4 + (threadIdx.x >> 6));
    const int beg = node << 6;
    const int cnt = deg[node];
    const int off = (lane < ACT ? lane : ACT - 1) * LPT;

    float acc[LPT];
#pragma unroll
    for (int j = 0; j < LPT; ++j) acc[j] = 0.0f;

    // ---- 16-deep batches ----
    const int nb = cnt >> 4;
    int idx[16];
    if (nb > 0) {
#pragma unroll
        for (int j = 0; j < 16; ++j) idx[j] = csr[beg + j];
    }
    for (int b = 0; b < nb; ++b) {
        unsigned lv[16][NW];
#pragma unroll
        for (int j = 0; j < 16; ++j) {
            const unsigned* p = (const unsigned*)(h + (size_t)idx[j] * D + off);
            if constexpr (NW == 2) {
                uint2 t = *(const uint2*)p;
                lv[j][0] = t.x; lv[j][1] = t.y;
            } else {
                lv[j][0] = *p;
            }
        }
        int nidx[16];
        const int nbase = beg + (b + 1) * 16;
        if (b + 1 < nb) {
#pragma unroll
            for (int j = 0; j < 16; ++j) nidx[j] = csr[nbase + j];
        }
#pragma unroll
        for (int j = 0; j < 16; ++j)
#pragma unroll
            for (int q = 0; q < NW; ++q) {
                unsigned u = lv[j][q];
                acc[2 * q]     += __uint_as_float(u << 16);
                acc[2 * q + 1] += __uint_as_float(u & 0xffff0000u);
            }
        if (b + 1 < nb) {
#pragma unroll
            for (int j = 0; j < 16; ++j) idx[j] = nidx[j];
        }
    }

    // ---- tail: one 8-deep batch, then scalar ----
    int tb = beg + (nb << 4);
    int rem = cnt & 15;
    if (rem >= 8) {
        int ti[8];
#pragma unroll
        for (int j = 0; j < 8; ++j) ti[j] = csr[tb + j];
        unsigned lv[8][NW];
#pragma unroll
        for (int j = 0; j < 8; ++j) {
            const unsigned* p = (const unsigned*)(h + (size_t)ti[j] * D + off);
            if constexpr (NW == 2) {
                uint2 t = *(const uint2*)p;
                lv[j][0] = t.x; lv[j][1] = t.y;
            } else {
                lv[j][0] = *p;
            }
        }
#pragma unroll
        for (int j = 0; j < 8; ++j)
#pragma unroll
            for (int q = 0; q < NW; ++q) {
                unsigned u = lv[j][q];
                acc[2 * q]     += __uint_as_float(u << 16);
                acc[2 * q + 1] += __uint_as_float(u & 0xffff0000u);
            }
        tb += 8;
        rem -= 8;
    }
    for (int t = 0; t < rem; ++t) {
        const unsigned* p = (const unsigned*)(h + (size_t)csr[tb + t] * D + off);
#pragma unroll
        for (int q = 0; q < NW; ++q) {
            unsigned u = p[q];
            acc[2 * q]     += __uint_as_float(u << 16);
            acc[2 * q + 1] += __uint_as_float(u & 0xffff0000u);
        }
    }

    if (lane < ACT) {
        float sc = inv_in[node];
        unsigned o[NW];
#pragma unroll
        for (int q = 0; q < NW; ++q)
            o[q] = (unsigned)f2b(acc[2 * q] * sc) | ((unsigned)f2b(acc[2 * q + 1] * sc) << 16);
        unsigned* dp = (unsigned*)(agg + (size_t)node * D + off);
        if constexpr (NW == 2) {
            uint2 t; t.x = o[0]; t.y = o[1];
            *(uint2*)dp = t;
        } else {
            *dp = o[0];
        }
    }
}

// ---------------- small tiled GEMM (32->32 and 64->96), bf16 output -------------------
template <int D_IN, int D_OUT, bool SCALE, bool BROW>
__global__ __launch_bounds__(256) void gemm_tile_k(
    const float* __restrict__ in, int in_stride,
    const float* __restrict__ W, const float* __restrict__ bias,
    const float* __restrict__ scale, const float* __restrict__ brow,
    const float* __restrict__ posts,
    u16* __restrict__ out, int out_stride, int n) {
    constexpr int TMW = 8;
    constexpr int ROWS = TMW * 4;
    constexpr int NOUT = (D_OUT + 63) / 64;
    __shared__ float s_in[ROWS * D_IN];

    const int tid = threadIdx.x;
    const int lane = tid & 63;
    const int wave = tid >> 6;
    const int row0 = blockIdx.x * ROWS;

    constexpr int NV = ROWS * D_IN / 4;
    for (int i = tid; i < NV; i += 256) {
        int m = i / (D_IN / 4);
        int kv = i % (D_IN / 4);
        int row = min(row0 + m, n - 1);
        float4 v = *(const float4*)(in + (size_t)row * in_stride + kv * 4);
        if (SCALE) {
            float s = scale[row];
            v.x *= s; v.y *= s; v.z *= s; v.w *= s;
        }
        *(float4*)(s_in + m * D_IN + kv * 4) = v;
    }
    __syncthreads();

    int f[NOUT], ff[NOUT];
    bool fok[NOUT];
    float bv[NOUT];
#pragma unroll
    for (int o = 0; o < NOUT; ++o) {
        f[o] = lane + 64 * o;
        fok[o] = (f[o] < D_OUT);
        ff[o] = fok[o] ? f[o] : 0;
        bv[o] = bias[ff[o]];
    }

    const float* s_my = s_in + wave * TMW * D_IN;

    float acc[NOUT][TMW];
#pragma unroll
    for (int o = 0; o < NOUT; ++o)
#pragma unroll
        for (int m = 0; m < TMW; ++m) acc[o][m] = 0.0f;

    for (int k = 0; k < D_IN; k += 4) {
        float w[4][NOUT];
#pragma unroll
        for (int j = 0; j < 4; ++j)
#pragma unroll
            for (int o = 0; o < NOUT; ++o) w[j][o] = W[(k + j) * D_OUT + ff[o]];
#pragma unroll
        for (int m = 0; m < TMW; ++m) {
            float4 a = *(const float4*)(s_my + m * D_IN + k);
#pragma unroll
            for (int o = 0; o < NOUT; ++o) {
                acc[o][m] = fmaf(a.x, w[0][o], acc[o][m]);
                acc[o][m] = fmaf(a.y, w[1][o], acc[o][m]);
                acc[o][m] = fmaf(a.z, w[2][o], acc[o][m]);
                acc[o][m] = fmaf(a.w, w[3][o], acc[o][m]);
            }
        }
    }

#pragma unroll
    for (int m = 0; m < TMW; ++m) {
        int row = row0 + wave * TMW + m;
        if (row < n) {
            float bc = BROW ? brow[row] : 1.0f;
            float pm = posts[row];
#pragma unroll
            for (int o = 0; o < NOUT; ++o) {
                if (!fok[o]) continue;
                float v = fmaxf(acc[o][m] + bv[o] * bc, 0.0f) * pm;
                out[(size_t)row * out_stride + f[o]] = f2b(v);
            }
        }
    }
}

// ---------------- pack W (fp32 [K][192]) into MFMA B-fragment order, bf16 ---------------
template <int K>
__global__ void pack_w_k(const float* __restrict__ W, u16* __restrict__ Wp) {
    constexpr int KS = K / 32;
    int idx = blockIdx.x * 256 + threadIdx.x;
    if (idx >= 12 * KS * 64) return;
    int l = idx & 63;
    int s = (idx >> 6) % KS;
    int t = (idx >> 6) / KS;
    int col = t * 16 + (l & 15);
    int krow = s * 32 + ((l >> 4) * 8);
    u16 tmp[8] __attribute__((aligned(16)));
#pragma unroll
    for (int j = 0; j < 8; ++j) tmp[j] = f2b(W[(size_t)(krow + j) * 192 + col]);
    *(uint4*)(Wp + (size_t)idx * 8) = *(const uint4*)tmp;
}

// ---------------- MFMA GEMM (conv0): h1 = bf16( relu(A@W + b) * inv_out ) ----------------
template <int K>
__global__ __launch_bounds__(256) void mfma_gemm_k(
    const u16* __restrict__ A, const u16* __restrict__ Wp,
    const float* __restrict__ bias, const float* __restrict__ posts,
    u16* __restrict__ outB, int n) {
    constexpr int KS = K / 32;
    const int tid = threadIdx.x;
    const int lane = tid & 63;
    const int w = tid >> 6;
    const int row0 = blockIdx.x * 16;
    const int arow = row0 + (lane & 15);
    const int kbase = (lane >> 4) * 8;

    f4_t acc[3];
#pragma unroll
    for (int o = 0; o < 3; ++o) acc[o] = (f4_t){0.f, 0.f, 0.f, 0.f};

    const u16* ap = A + (size_t)arow * K + kbase;
#pragma unroll
    for (int s = 0; s < KS; ++s) {
        bf8_t af = *(const bf8_t*)(ap + s * 32);
#pragma unroll
        for (int o = 0; o < 3; ++o) {
            int t = w * 3 + o;
            bf8_t bf = *(const bf8_t*)(Wp + (size_t)((t * KS + s) * 64 + lane) * 8);
            acc[o] = __builtin_amdgcn_mfma_f32_16x16x32_bf16(af, bf, acc[o], 0, 0, 0);
        }
    }

    const int drow = row0 + (lane >> 4) * 4;
    const int dcol = lane & 15;
    float pm[4];
#pragma unroll
    for (int r = 0; r < 4; ++r) pm[r] = posts[drow + r];
#pragma unroll
    for (int o = 0; o < 3; ++o) {
        int col = (w * 3 + o) * 16 + dcol;
        float bv = bias[col];
#pragma unroll
        for (int r = 0; r < 4; ++r) {
            float v = fmaxf(acc[o][r] + bv, 0.0f) * pm[r];
            outB[(size_t)(drow + r) * 192 + col] = f2b(v);
        }
    }
}

// ---------------- fused MFMA: conv1 GEMM + linear GEMM + head (192->192->192->2) ---------
__global__ __launch_bounds__(256) void mfma_fused_k(
    const u16* __restrict__ A,  // [n,192] bf16 (inv_in pre-scaled)
    const u16* __restrict__ Wp1, const float* __restrict__ b1,
    const u16* __restrict__ Wp2, const float* __restrict__ b2,
    const float* __restrict__ Wo, const float* __restrict__ bo,
    float* __restrict__ out, int n) {
    constexpr int KS = 6;       // 192/32
    constexpr int S = 200;      // LDS row stride
    __shared__ float sbuf[16 * S];
    __shared__ float s_head[16][17][2];

    const int tid = threadIdx.x;
    const int lane = tid & 63;
    const int w = tid >> 6;
    const int row0 = blockIdx.x * 16;
    const int arow = row0 + (lane & 15);
    const int kbase = (lane >> 4) * 8;
    const int drow = (lane >> 4) * 4;
    const int dcol = lane & 15;

    f4_t acc[3];
#pragma unroll
    for (int o = 0; o < 3; ++o) acc[o] = (f4_t){0.f, 0.f, 0.f, 0.f};

    // ---- GEMM 1: A (global bf16) @ W1 ----
    const u16* ap = A + (size_t)arow * 192 + kbase;
#pragma unroll
    for (int s = 0; s < KS; ++s) {
        bf8_t af = *(const bf8_t*)(ap + s * 32);
#pragma unroll
        for (int o = 0; o < 3; ++o) {
            int t = w * 3 + o;
            bf8_t bf = *(const bf8_t*)(Wp1 + (size_t)((t * KS + s) * 64 + lane) * 8);
            acc[o] = __builtin_amdgcn_mfma_f32_16x16x32_bf16(af, bf, acc[o], 0, 0, 0);
        }
    }

    // h2 = relu(acc + b1) -> LDS (bf16)
    u16* h2 = (u16*)sbuf;
#pragma unroll
    for (int o = 0; o < 3; ++o) {
        int col = (w * 3 + o) * 16 + dcol;
        float bv = b1[col];
#pragma unroll
        for (int r = 0; r < 4; ++r)
            h2[(drow + r) * S + col] = f2b(fmaxf(acc[o][r] + bv, 0.0f));
    }
    __syncthreads();

    // ---- GEMM 2: h2 (LDS bf16) @ W2 ----
#pragma unroll
    for (int o = 0; o < 3; ++o) acc[o] = (f4_t){0.f, 0.f, 0.f, 0.f};
    const u16* hp = h2 + (lane & 15) * S + kbase;
#pragma unroll
    for (int s = 0; s < KS; ++s) {
        bf8_t af = *(const bf8_t*)(hp + s * 32);
#pragma unroll
        for (int o = 0; o < 3; ++o) {
            int t = w * 3 + o;
            bf8_t bf = *(const bf8_t*)(Wp2 + (size_t)((t * KS + s) * 64 + lane) * 8);
            acc[o] = __builtin_amdgcn_mfma_f32_16x16x32_bf16(af, bf, acc[o], 0, 0, 0);
        }
    }
    __syncthreads();  // all h2 reads done before overwriting sbuf as f32

    // h3 = relu(acc + b2) -> LDS (f32)
#pragma unroll
    for (int o = 0; o < 3; ++o) {
        int col = (w * 3 + o) * 16 + dcol;
        float bv = b2[col];
#pragma unroll
        for (int r = 0; r < 4; ++r)
            sbuf[(drow + r) * S + col] = fmaxf(acc[o][r] + bv, 0.0f);
    }
    __syncthreads();

    // ---- head: out = h3 @ Wo + bo ----
    {
        int r = tid >> 4;
        int seg = tid & 15;
        const float* hr = sbuf + r * S + seg * 12;
        const float* wor = Wo + seg * 24;
        float p0 = 0.0f, p1 = 0.0f;
#pragma unroll
        for (int c = 0; c < 12; ++c) {
            float hv = hr[c];
            p0 = fmaf(hv, wor[c * 2 + 0], p0);
            p1 = fmaf(hv, wor[c * 2 + 1], p1);
        }
        s_head[r][seg][0] = p0;
        s_head[r][seg][1] = p1;
    }
    __syncthreads();
    if (tid < 32) {
        int r = tid >> 1, c = tid & 1;
        float sum = bo[c];
#pragma unroll
        for (int g = 0; g < 16; ++g) sum += s_head[r][g][c];
        int row = row0 + r;
        if (row < n) out[(size_t)row * 2 + c] = sum;
    }
}

extern "C" void kernel_launch(void* const* d_in, const int* in_sizes, int n_in,
                              void* d_out, int out_size, void* d_ws, size_t ws_size,
                              hipStream_t stream) {
    const float* node_feats = (const float*)d_in[0];   // [N,64]
    const float* edge_feats = (const float*)d_in[1];   // [E,32]
    const float* Wn  = (const float*)d_in[2];          // [64,96]
    const float* bn  = (const float*)d_in[3];
    const float* We  = (const float*)d_in[4];          // [32,32]
    const float* be  = (const float*)d_in[5];
    const float* Wc0 = (const float*)d_in[6];          // [128,192]
    const float* bc0 = (const float*)d_in[7];
    const float* Wc1 = (const float*)d_in[8];          // [192,192]
    const float* bc1 = (const float*)d_in[9];
    const float* Wl0 = (const float*)d_in[10];         // [192,192]
    const float* bl0 = (const float*)d_in[11];
    const float* Wo  = (const float*)d_in[12];         // [192,2]
    const float* bo  = (const float*)d_in[13];
    const int* src = (const int*)d_in[14];
    const int* dst = (const int*)d_in[15];
    float* out = (float*)d_out;

    const int N = NN, E = NE;

    // ---- workspace layout (16B-aligned sections) ----
    // zeroed prefix: [deg_out | bktc | efa]  (N + NBKT_PAD + 32N ints ~ 6.6 MB)
    int* dout      = (int*)d_ws;               // N (zeroed) -> deg_out
    int* bktc      = dout + N;                 // NBKT_PAD (zeroed) -> bucket cursors
    float* efa     = (float*)(bktc + NBKT_PAD);// 32N (zeroed) -> atomic edge-feat sums
    int* din       = (int*)(efa + (size_t)32 * N); // N deg_in (written by fill_k)
    int* csr       = din + N;                  // CAP*N ints {src} (padded CSR)
    float* inv_in   = (float*)(csr + (size_t)CAP * N);  // N
    float* inv_out  = inv_in + N;              // N
    float* inv_mean = inv_out + N;             // N
    float* bcoef    = inv_mean + N;            // N
    u16* h0   = (u16*)(bcoef + N);             // [N,128] bf16 (x inv_out)
    u16* aggA = h0 + (size_t)128 * N;          // [N,128] bf16 (x inv_in)
    u16* h1   = aggA + (size_t)128 * N;        // [N,192] bf16 (x inv_out)
    u16* aggB = h1 + (size_t)192 * N;          // [N,192] bf16 (x inv_in)
    u16* Wp0  = aggB + (size_t)192 * N;        // 128*192
    u16* Wp1  = Wp0 + 128 * 192;               // 192*192
    u16* Wp2  = Wp1 + 192 * 192;               // 192*192
    // partition buffer (4.8 MB u32) aliases h1 (19.2 MB): consumed by fill_k long
    // before mfma_gemm_k writes h1. Alignment fine (h1 offset is 16B-multiple).
    u32* part = (u32*)h1;

    hipMemsetAsync(d_ws, 0, (size_t)(N + NBKT_PAD + (size_t)32 * N) * sizeof(int), stream);

    const int GB32 = (N + 31) / 32;   // small-GEMM grid
    const int GB16 = N / 16;          // mfma grid (3125, exact)
    const int GW4  = (N + 3) / 4;     // wave-per-node gather grid (12500)
    const int GEA  = (E / 32 + 3) / 4;// edge_agg grid: 1 wave per 32 edges (6250)

    // weight packing (tiny, every launch)
    pack_w_k<128><<<dim3(12), dim3(256), 0, stream>>>(Wc0, Wp0);
    pack_w_k<192><<<dim3(18), dim3(256), 0, stream>>>(Wc1, Wp1);
    pack_w_k<192><<<dim3(18), dim3(256), 0, stream>>>(Wl0, Wp2);

    // streaming edge-feature aggregation (sequential ef reads + f32 atomics into efa)
    edge_agg_k<<<dim3(GEA), dim3(256), 0, stream>>>(edge_feats, dst, efa, E);

    // two-pass bucketed build: partition by dst bucket, then L2-local CSR fill
    partition_k<<<dim3((E + CHUNK - 1) / CHUNK), dim3(256), 0, stream>>>(
        src, dst, dout, bktc, part, E);
    fill_k<<<dim3(NBKT), dim3(256), 0, stream>>>(part, bktc, csr, din, N);
    make_inv_k<<<dim3((N + 255) / 256), dim3(256), 0, stream>>>(din, dout, inv_in, inv_out,
                                                                inv_mean, bcoef, N);

    // h0[:,0:32] = bf16( relu((efa*inv_mean)@We + bcoef*be) * inv_out )
    gemm_tile_k<32, 32, true, true><<<dim3(GB32), dim3(256), 0, stream>>>(
        efa, 32, We, be, inv_mean, bcoef, inv_out, h0, 128, N);
    // h0[:,32:128] = bf16( relu(node_feats@Wn + bn) * inv_out )
    gemm_tile_k<64, 96, false, false><<<dim3(GB32), dim3(256), 0, stream>>>(
        node_feats, 64, Wn, bn, nullptr, nullptr, inv_out, h0 + 32, 128, N);

    // conv0: bf16 gather h0 -> aggA (x inv_in), MFMA GEMM 128->192 -> h1 (x inv_out)
    gather_b2_k<128, 2><<<dim3(GW4), dim3(256), 0, stream>>>(h0, csr, din, inv_in, aggA);
    mfma_gemm_k<128><<<dim3(GB16), dim3(256), 0, stream>>>(aggA, Wp0, bc0, inv_out, h1, N);

    // conv1: bf16 gather h1 -> aggB (x inv_in), fused MFMA (conv1 + linear + head) -> out
    gather_b2_k<192, 4><<<dim3(GW4), dim3(256), 0, stream>>>(h1, csr, din, inv_in, aggB);
    mfma_fused_k<<<dim3(GB16), dim3(256), 0, stream>>>(aggB, Wp1, bc1, Wp2, bl0, Wo, bo,
                                                       out, N);
}

// Round 4
// 429.576 us; speedup vs baseline: 1.0614x; 1.0614x over previous
//
#include <hip/hip_runtime.h>

#define NN 50000
#define NE 800000
#define CAP 64          // padded CSR slots per node (max deg_in ~40 for Poisson(16))

// ---- bucketed build parameters ----
#define NPB 128         // nodes per bucket (dst >> 7)
#define NBKT 391        // ceil(NN / NPB)
#define NBKT_PAD 512
#define BCAP 3072       // partition slots per bucket (mean 2048, sigma ~45 -> 22 sigma margin)
#define CHUNK 4096      // edges per partition block

typedef unsigned short u16;
typedef unsigned int u32;
typedef unsigned long long u64;
typedef __attribute__((ext_vector_type(8))) short bf8_t;   // 8 x bf16 (4 VGPRs)
typedef __attribute__((ext_vector_type(4))) float f4_t;    // 4 x f32 acc

__device__ __forceinline__ u16 f2b(float f) {              // RNE fp32 -> bf16
    unsigned u = __float_as_uint(f);
    unsigned r = u + 0x7FFF + ((u >> 16) & 1);
    return (u16)(r >> 16);
}

// ---------------- pass A: LDS-staged partition of edges into dst-buckets ----------------
// Packs {eid:32 | dst:16 | src:16} into u64; copy-out is bucket-contiguous bursts so HBM
// lines fill fully (the old random 8B scatter had 12x write amplification).
// Also builds deg_out histogram.
__global__ __launch_bounds__(256) void partition_k(
    const int* __restrict__ src, const int* __restrict__ dst,
    int* __restrict__ deg_out, int* __restrict__ bktc,
    u64* __restrict__ part, int E) {
    __shared__ unsigned cnt[NBKT_PAD];
    __shared__ unsigned base[NBKT_PAD];
    __shared__ unsigned cur[NBKT_PAD];
    __shared__ unsigned gbase[NBKT_PAD];
    __shared__ unsigned wtot[4];
    __shared__ u64 staged[CHUNK];

    const int tid = threadIdx.x;
    const int lane = tid & 63;
    const int wid = tid >> 6;
    const int e0 = blockIdx.x * CHUNK;
    const int n = min(CHUNK, E - e0);

    for (int i = tid; i < NBKT_PAD; i += 256) cnt[i] = 0;
    __syncthreads();

    // histogram buckets for this chunk
    for (int i = tid; i < n; i += 256) {
        int d = dst[e0 + i];
        atomicAdd(&cnt[d >> 7], 1u);
    }
    __syncthreads();

    // exclusive scan cnt[0..511] -> base (pairs per thread + shfl wave scan)
    {
        unsigned a = cnt[2 * tid];
        unsigned b = cnt[2 * tid + 1];
        unsigned ps = a + b;
        unsigned inc = ps;
#pragma unroll
        for (int d = 1; d < 64; d <<= 1) {
            unsigned v = __shfl_up(inc, d);
            if (lane >= d) inc += v;
        }
        if (lane == 63) wtot[wid] = inc;
        __syncthreads();
        unsigned wb = 0;
#pragma unroll
        for (int k = 0; k < 4; ++k) wb += (k < wid) ? wtot[k] : 0;
        unsigned eb = wb + inc - ps;        // exclusive base of pair slot 2*tid
        base[2 * tid] = eb;
        base[2 * tid + 1] = eb + a;
        cur[2 * tid] = eb;
        cur[2 * tid + 1] = eb + a;
    }
    __syncthreads();

    // scatter into LDS staging, bucket-sorted; deg_out histogram on the side
    for (int i = tid; i < n; i += 256) {
        int e = e0 + i;
        int d = dst[e];
        int s = src[e];
        atomicAdd(deg_out + s, 1);
        unsigned p = atomicAdd(&cur[d >> 7], 1u);
        staged[p] = ((u64)(unsigned)e << 32) | (((u32)d << 16) | (u32)s);
    }
    __syncthreads();

    // reserve global space per bucket
    for (int b = tid; b < NBKT; b += 256) {
        unsigned c = cur[b] - base[b];
        if (c) gbase[b] = (unsigned)atomicAdd(&bktc[b], (int)c);
    }
    __syncthreads();

    // copy out: consecutive i within a bucket -> consecutive global slots (bursts)
    for (int i = tid; i < n; i += 256) {
        u64 v = staged[i];
        int b = (int)((v >> 16) & 0xffffu) >> 7;
        unsigned idx = gbase[b] + ((unsigned)i - base[b]);
        if (idx < BCAP) part[(size_t)b * BCAP + idx] = v;
    }
}

// ---------------- pass B: per-bucket CSR fill (L2-resident windows) ----------------
// One block per bucket; writes parallel src/eid CSRs; LDS cursors give deg_in free.
// Zero-pads csr_eid up to the 32-slot batch boundary so gather_e4_k can issue
// UNCONDITIONAL batched loads (pad slots hit the cached ef row 0, adds are masked).
__global__ __launch_bounds__(256) void fill_k(
    const u64* __restrict__ part, const int* __restrict__ bktc,
    int* __restrict__ csr_src, int* __restrict__ csr_eid,
    int* __restrict__ din, int n) {
    __shared__ unsigned cur[NPB];
    const int tid = threadIdx.x;
    const int b = blockIdx.x;
    const int node0 = b << 7;
    if (tid < NPB) cur[tid] = 0;
    __syncthreads();

    const int cnt = min(bktc[b], BCAP);
    const u64* p = part + (size_t)b * BCAP;
    for (int i = tid; i < cnt; i += 256) {
        u64 v = p[i];
        int s = (int)(v & 0xffffu);
        int d = (int)((v >> 16) & 0xffffu);
        int e = (int)(v >> 32);
        unsigned q = atomicAdd(&cur[d & (NPB - 1)], 1u);
        if (q < CAP) {
            csr_src[((size_t)d << 6) + q] = s;
            csr_eid[((size_t)d << 6) + q] = e;
        }
    }
    __syncthreads();
    if (tid < NPB) {
        int node = node0 + tid;
        if (node < n) {
            unsigned cq = min(cur[tid], (unsigned)CAP);
            din[node] = (int)cq;
            int end = (cq <= 32u) ? 32 : 64;
            for (int q = (int)cq; q < end; ++q)
                csr_eid[((size_t)node << 6) + q] = 0;
        }
    }
}

__global__ void make_inv_k(const int* __restrict__ deg_in, const int* __restrict__ deg_out,
                           float* __restrict__ inv_in, float* __restrict__ inv_out,
                           float* __restrict__ inv_mean, float* __restrict__ bcoef, int n) {
    int i = blockIdx.x * 256 + threadIdx.x;
    if (i < n) {
        int d_in = deg_in[i];
        float di = fmaxf((float)d_in, 1.0f);
        float dq = fmaxf((float)deg_out[i], 1.0f);
        inv_in[i]   = 1.0f / sqrtf(di);
        inv_out[i]  = 1.0f / sqrtf(dq);
        inv_mean[i] = 1.0f / di;
        bcoef[i]    = (d_in > 0) ? 1.0f : 0.0f;
    }
}

// ---------------- fp32 edge-feat gather: wave-per-node, 4 rows/instr via float2 ---------
// Fixed unconditional 32-slot batch (pad eids are 0 -> cached row, masked adds):
// 32 rows (4 KB) in flight per wave, half the vmem instructions of the 2-row version.
__global__ __launch_bounds__(256) void gather_e4_k(
    const float* __restrict__ ef, const int* __restrict__ csr_eid,
    const int* __restrict__ deg, float* __restrict__ efa) {
    const int lane = threadIdx.x & 63;
    const int node = __builtin_amdgcn_readfirstlane(blockIdx.x * 4 + (threadIdx.x >> 6));
    const int beg = node << 6;
    const int cnt = deg[node];
    const int g = lane >> 4;            // row group 0..3
    const int c = (lane & 15) * 2;      // float2 column pair

    float ax = 0.0f, ay = 0.0f;
    {
        int eidv[8];
#pragma unroll
        for (int j = 0; j < 8; ++j) eidv[j] = csr_eid[beg + 4 * j + g];
        float2 v[8];
#pragma unroll
        for (int j = 0; j < 8; ++j)
            v[j] = *(const float2*)(ef + (size_t)eidv[j] * 32 + c);
#pragma unroll
        for (int j = 0; j < 8; ++j)
            if (4 * j + g < cnt) { ax += v[j].x; ay += v[j].y; }
    }
    if (cnt > 32) {                     // rare (P(deg>32) ~ 1e-4), wave-uniform
        int eidv[8];
#pragma unroll
        for (int j = 0; j < 8; ++j) eidv[j] = csr_eid[beg + 32 + 4 * j + g];
        float2 v[8];
#pragma unroll
        for (int j = 0; j < 8; ++j)
            v[j] = *(const float2*)(ef + (size_t)eidv[j] * 32 + c);
#pragma unroll
        for (int j = 0; j < 8; ++j)
            if (32 + 4 * j + g < cnt) { ax += v[j].x; ay += v[j].y; }
    }
    // reduce the 4 row-groups
    ax += __shfl_down(ax, 16); ay += __shfl_down(ay, 16);
    ax += __shfl_down(ax, 32); ay += __shfl_down(ay, 32);
    if (lane < 16) {
        float2 o; o.x = ax; o.y = ay;
        *(float2*)(efa + (size_t)node * 32 + c) = o;
    }
}

// ---------------- bf16 gather, wave-per-node, 16-deep batches ----------------
// agg[d] = bf16( inv_in[d] * sum_e h[src_e] );  h pre-scaled by inv_out.
template <int D, int LPT>
__global__ __launch_bounds__(256) void gather_b2_k(
    const u16* __restrict__ h, const int* __restrict__ csr,
    const int* __restrict__ deg, const float* __restrict__ inv_in,
    u16* __restrict__ agg) {
    constexpr int ACT = D / LPT;
    constexpr int NW = LPT / 2;          // uints per lane-load
    const int lane = threadIdx.x & 63;
    const int node = __builtin_amdgcn_readfirstlane(blockIdx.x * 4 + (threadIdx.x >> 6));
    const int beg = node << 6;
    const int cnt = deg[node];
    const int off = (lane < ACT ? lane : ACT - 1) * LPT;

    float acc[LPT];
#pragma unroll
    for (int j = 0; j < LPT; ++j) acc[j] = 0.0f;

    // ---- 16-deep batches ----
    const int nb = cnt >> 4;
    int idx[16];
    if (nb > 0) {
#pragma unroll
        for (int j = 0; j < 16; ++j) idx[j] = csr[beg + j];
    }
    for (int b = 0; b < nb; ++b) {
        unsigned lv[16][NW];
#pragma unroll
        for (int j = 0; j < 16; ++j) {
            const unsigned* p = (const unsigned*)(h + (size_t)idx[j] * D + off);
            if constexpr (NW == 2) {
                uint2 t = *(const uint2*)p;
                lv[j][0] = t.x; lv[j][1] = t.y;
            } else {
                lv[j][0] = *p;
            }
        }
        int nidx[16];
        const int nbase = beg + (b + 1) * 16;
        if (b + 1 < nb) {
#pragma unroll
            for (int j = 0; j < 16; ++j) nidx[j] = csr[nbase + j];
        }
#pragma unroll
        for (int j = 0; j < 16; ++j)
#pragma unroll
            for (int q = 0; q < NW; ++q) {
                unsigned u = lv[j][q];
                acc[2 * q]     += __uint_as_float(u << 16);
                acc[2 * q + 1] += __uint_as_float(u & 0xffff0000u);
            }
        if (b + 1 < nb) {
#pragma unroll
            for (int j = 0; j < 16; ++j) idx[j] = nidx[j];
        }
    }

    // ---- tail: one 8-deep batch, then scalar ----
    int tb = beg + (nb << 4);
    int rem = cnt & 15;
    if (rem >= 8) {
        int ti[8];
#pragma unroll
        for (int j = 0; j < 8; ++j) ti[j] = csr[tb + j];
        unsigned lv[8][NW];
#pragma unroll
        for (int j = 0; j < 8; ++j) {
            const unsigned* p = (const unsigned*)(h + (size_t)ti[j] * D + off);
            if constexpr (NW == 2) {
                uint2 t = *(const uint2*)p;
                lv[j][0] = t.x; lv[j][1] = t.y;
            } else {
                lv[j][0] = *p;
            }
        }
#pragma unroll
        for (int j = 0; j < 8; ++j)
#pragma unroll
            for (int q = 0; q < NW; ++q) {
                unsigned u = lv[j][q];
                acc[2 * q]     += __uint_as_float(u << 16);
                acc[2 * q + 1] += __uint_as_float(u & 0xffff0000u);
            }
        tb += 8;
        rem -= 8;
    }
    for (int t = 0; t < rem; ++t) {
        const unsigned* p = (const unsigned*)(h + (size_t)csr[tb + t] * D + off);
#pragma unroll
        for (int q = 0; q < NW; ++q) {
            unsigned u = p[q];
            acc[2 * q]     += __uint_as_float(u << 16);
            acc[2 * q + 1] += __uint_as_float(u & 0xffff0000u);
        }
    }

    if (lane < ACT) {
        float sc = inv_in[node];
        unsigned o[NW];
#pragma unroll
        for (int q = 0; q < NW; ++q)
            o[q] = (unsigned)f2b(acc[2 * q] * sc) | ((unsigned)f2b(acc[2 * q + 1] * sc) << 16);
        unsigned* dp = (unsigned*)(agg + (size_t)node * D + off);
        if constexpr (NW == 2) {
            uint2 t; t.x = o[0]; t.y = o[1];
            *(uint2*)dp = t;
        } else {
            *dp = o[0];
        }
    }
}

// ---------------- small tiled GEMM (32->32 and 64->96), bf16 output -------------------
template <int D_IN, int D_OUT, bool SCALE, bool BROW>
__global__ __launch_bounds__(256) void gemm_tile_k(
    const float* __restrict__ in, int in_stride,
    const float* __restrict__ W, const float* __restrict__ bias,
    const float* __restrict__ scale, const float* __restrict__ brow,
    const float* __restrict__ posts,
    u16* __restrict__ out, int out_stride, int n) {
    constexpr int TMW = 8;
    constexpr int ROWS = TMW * 4;
    constexpr int NOUT = (D_OUT + 63) / 64;
    __shared__ float s_in[ROWS * D_IN];

    const int tid = threadIdx.x;
    const int lane = tid & 63;
    const int wave = tid >> 6;
    const int row0 = blockIdx.x * ROWS;

    constexpr int NV = ROWS * D_IN / 4;
    for (int i = tid; i < NV; i += 256) {
        int m = i / (D_IN / 4);
        int kv = i % (D_IN / 4);
        int row = min(row0 + m, n - 1);
        float4 v = *(const float4*)(in + (size_t)row * in_stride + kv * 4);
        if (SCALE) {
            float s = scale[row];
            v.x *= s; v.y *= s; v.z *= s; v.w *= s;
        }
        *(float4*)(s_in + m * D_IN + kv * 4) = v;
    }
    __syncthreads();

    int f[NOUT], ff[NOUT];
    bool fok[NOUT];
    float bv[NOUT];
#pragma unroll
    for (int o = 0; o < NOUT; ++o) {
        f[o] = lane + 64 * o;
        fok[o] = (f[o] < D_OUT);
        ff[o] = fok[o] ? f[o] : 0;
        bv[o] = bias[ff[o]];
    }

    const float* s_my = s_in + wave * TMW * D_IN;

    float acc[NOUT][TMW];
#pragma unroll
    for (int o = 0; o < NOUT; ++o)
#pragma unroll
        for (int m = 0; m < TMW; ++m) acc[o][m] = 0.0f;

    for (int k = 0; k < D_IN; k += 4) {
        float w[4][NOUT];
#pragma unroll
        for (int j = 0; j < 4; ++j)
#pragma unroll
            for (int o = 0; o < NOUT; ++o) w[j][o] = W[(k + j) * D_OUT + ff[o]];
#pragma unroll
        for (int m = 0; m < TMW; ++m) {
            float4 a = *(const float4*)(s_my + m * D_IN + k);
#pragma unroll
            for (int o = 0; o < NOUT; ++o) {
                acc[o][m] = fmaf(a.x, w[0][o], acc[o][m]);
                acc[o][m] = fmaf(a.y, w[1][o], acc[o][m]);
                acc[o][m] = fmaf(a.z, w[2][o], acc[o][m]);
                acc[o][m] = fmaf(a.w, w[3][o], acc[o][m]);
            }
        }
    }

#pragma unroll
    for (int m = 0; m < TMW; ++m) {
        int row = row0 + wave * TMW + m;
        if (row < n) {
            float bc = BROW ? brow[row] : 1.0f;
            float pm = posts[row];
#pragma unroll
            for (int o = 0; o < NOUT; ++o) {
                if (!fok[o]) continue;
                float v = fmaxf(acc[o][m] + bv[o] * bc, 0.0f) * pm;
                out[(size_t)row * out_stride + f[o]] = f2b(v);
            }
        }
    }
}

// ---------------- pack W (fp32 [K][192]) into MFMA B-fragment order, bf16 ---------------
template <int K>
__global__ void pack_w_k(const float* __restrict__ W, u16* __restrict__ Wp) {
    constexpr int KS = K / 32;
    int idx = blockIdx.x * 256 + threadIdx.x;
    if (idx >= 12 * KS * 64) return;
    int l = idx & 63;
    int s = (idx >> 6) % KS;
    int t = (idx >> 6) / KS;
    int col = t * 16 + (l & 15);
    int krow = s * 32 + ((l >> 4) * 8);
    u16 tmp[8] __attribute__((aligned(16)));
#pragma unroll
    for (int j = 0; j < 8; ++j) tmp[j] = f2b(W[(size_t)(krow + j) * 192 + col]);
    *(uint4*)(Wp + (size_t)idx * 8) = *(const uint4*)tmp;
}

// ---------------- MFMA GEMM (conv0): h1 = bf16( relu(A@W + b) * inv_out ) ----------------
template <int K>
__global__ __launch_bounds__(256) void mfma_gemm_k(
    const u16* __restrict__ A, const u16* __restrict__ Wp,
    const float* __restrict__ bias, const float* __restrict__ posts,
    u16* __restrict__ outB, int n) {
    constexpr int KS = K / 32;
    const int tid = threadIdx.x;
    const int lane = tid & 63;
    const int w = tid >> 6;
    const int row0 = blockIdx.x * 16;
    const int arow = row0 + (lane & 15);
    const int kbase = (lane >> 4) * 8;

    f4_t acc[3];
#pragma unroll
    for (int o = 0; o < 3; ++o) acc[o] = (f4_t){0.f, 0.f, 0.f, 0.f};

    const u16* ap = A + (size_t)arow * K + kbase;
#pragma unroll
    for (int s = 0; s < KS; ++s) {
        bf8_t af = *(const bf8_t*)(ap + s * 32);
#pragma unroll
        for (int o = 0; o < 3; ++o) {
            int t = w * 3 + o;
            bf8_t bf = *(const bf8_t*)(Wp + (size_t)((t * KS + s) * 64 + lane) * 8);
            acc[o] = __builtin_amdgcn_mfma_f32_16x16x32_bf16(af, bf, acc[o], 0, 0, 0);
        }
    }

    const int drow = row0 + (lane >> 4) * 4;
    const int dcol = lane & 15;
    float pm[4];
#pragma unroll
    for (int r = 0; r < 4; ++r) pm[r] = posts[drow + r];
#pragma unroll
    for (int o = 0; o < 3; ++o) {
        int col = (w * 3 + o) * 16 + dcol;
        float bv = bias[col];
#pragma unroll
        for (int r = 0; r < 4; ++r) {
            float v = fmaxf(acc[o][r] + bv, 0.0f) * pm[r];
            outB[(size_t)(drow + r) * 192 + col] = f2b(v);
        }
    }
}

// ---------------- fused MFMA: conv1 GEMM + linear GEMM + head (192->192->192->2) ---------
__global__ __launch_bounds__(256) void mfma_fused_k(
    const u16* __restrict__ A,  // [n,192] bf16 (inv_in pre-scaled)
    const u16* __restrict__ Wp1, const float* __restrict__ b1,
    const u16* __restrict__ Wp2, const float* __restrict__ b2,
    const float* __restrict__ Wo, const float* __restrict__ bo,
    float* __restrict__ out, int n) {
    constexpr int KS = 6;       // 192/32
    constexpr int S = 200;      // LDS row stride
    __shared__ float sbuf[16 * S];
    __shared__ float s_head[16][17][2];

    const int tid = threadIdx.x;
    const int lane = tid & 63;
    const int w = tid >> 6;
    const int row0 = blockIdx.x * 16;
    const int arow = row0 + (lane & 15);
    const int kbase = (lane >> 4) * 8;
    const int drow = (lane >> 4) * 4;
    const int dcol = lane & 15;

    f4_t acc[3];
#pragma unroll
    for (int o = 0; o < 3; ++o) acc[o] = (f4_t){0.f, 0.f, 0.f, 0.f};

    // ---- GEMM 1: A (global bf16) @ W1 ----
    const u16* ap = A + (size_t)arow * 192 + kbase;
#pragma unroll
    for (int s = 0; s < KS; ++s) {
        bf8_t af = *(const bf8_t*)(ap + s * 32);
#pragma unroll
        for (int o = 0; o < 3; ++o) {
            int t = w * 3 + o;
            bf8_t bf = *(const bf8_t*)(Wp1 + (size_t)((t * KS + s) * 64 + lane) * 8);
            acc[o] = __builtin_amdgcn_mfma_f32_16x16x32_bf16(af, bf, acc[o], 0, 0, 0);
        }
    }

    // h2 = relu(acc + b1) -> LDS (bf16)
    u16* h2 = (u16*)sbuf;
#pragma unroll
    for (int o = 0; o < 3; ++o) {
        int col = (w * 3 + o) * 16 + dcol;
        float bv = b1[col];
#pragma unroll
        for (int r = 0; r < 4; ++r)
            h2[(drow + r) * S + col] = f2b(fmaxf(acc[o][r] + bv, 0.0f));
    }
    __syncthreads();

    // ---- GEMM 2: h2 (LDS bf16) @ W2 ----
#pragma unroll
    for (int o = 0; o < 3; ++o) acc[o] = (f4_t){0.f, 0.f, 0.f, 0.f};
    const u16* hp = h2 + (lane & 15) * S + kbase;
#pragma unroll
    for (int s = 0; s < KS; ++s) {
        bf8_t af = *(const bf8_t*)(hp + s * 32);
#pragma unroll
        for (int o = 0; o < 3; ++o) {
            int t = w * 3 + o;
            bf8_t bf = *(const bf8_t*)(Wp2 + (size_t)((t * KS + s) * 64 + lane) * 8);
            acc[o] = __builtin_amdgcn_mfma_f32_16x16x32_bf16(af, bf, acc[o], 0, 0, 0);
        }
    }
    __syncthreads();  // all h2 reads done before overwriting sbuf as f32

    // h3 = relu(acc + b2) -> LDS (f32)
#pragma unroll
    for (int o = 0; o < 3; ++o) {
        int col = (w * 3 + o) * 16 + dcol;
        float bv = b2[col];
#pragma unroll
        for (int r = 0; r < 4; ++r)
            sbuf[(drow + r) * S + col] = fmaxf(acc[o][r] + bv, 0.0f);
    }
    __syncthreads();

    // ---- head: out = h3 @ Wo + bo ----
    {
        int r = tid >> 4;
        int seg = tid & 15;
        const float* hr = sbuf + r * S + seg * 12;
        const float* wor = Wo + seg * 24;
        float p0 = 0.0f, p1 = 0.0f;
#pragma unroll
        for (int c = 0; c < 12; ++c) {
            float hv = hr[c];
            p0 = fmaf(hv, wor[c * 2 + 0], p0);
            p1 = fmaf(hv, wor[c * 2 + 1], p1);
        }
        s_head[r][seg][0] = p0;
        s_head[r][seg][1] = p1;
    }
    __syncthreads();
    if (tid < 32) {
        int r = tid >> 1, c = tid & 1;
        float sum = bo[c];
#pragma unroll
        for (int g = 0; g < 16; ++g) sum += s_head[r][g][c];
        int row = row0 + r;
        if (row < n) out[(size_t)row * 2 + c] = sum;
    }
}

extern "C" void kernel_launch(void* const* d_in, const int* in_sizes, int n_in,
                              void* d_out, int out_size, void* d_ws, size_t ws_size,
                              hipStream_t stream) {
    const float* node_feats = (const float*)d_in[0];   // [N,64]
    const float* edge_feats = (const float*)d_in[1];   // [E,32]
    const float* Wn  = (const float*)d_in[2];          // [64,96]
    const float* bn  = (const float*)d_in[3];
    const float* We  = (const float*)d_in[4];          // [32,32]
    const float* be  = (const float*)d_in[5];
    const float* Wc0 = (const float*)d_in[6];          // [128,192]
    const float* bc0 = (const float*)d_in[7];
    const float* Wc1 = (const float*)d_in[8];          // [192,192]
    const float* bc1 = (const float*)d_in[9];
    const float* Wl0 = (const float*)d_in[10];         // [192,192]
    const float* bl0 = (const float*)d_in[11];
    const float* Wo  = (const float*)d_in[12];         // [192,2]
    const float* bo  = (const float*)d_in[13];
    const int* src = (const int*)d_in[14];
    const int* dst = (const int*)d_in[15];
    float* out = (float*)d_out;

    const int N = NN, E = NE;

    // ---- workspace layout (16B-aligned sections) ----
    // zeroed prefix: [deg_out | bktc]  (tiny)
    int* dout      = (int*)d_ws;               // N (zeroed) -> deg_out
    int* bktc      = dout + N;                 // NBKT_PAD (zeroed) -> bucket cursors
    int* din       = bktc + NBKT_PAD;          // N deg_in (written by fill_k)
    int* csr_src   = din + N;                  // CAP*N ints (padded CSR, src ids)
    int* csr_eid   = csr_src + (size_t)CAP * N;// CAP*N ints (padded CSR, edge ids; 0-padded)
    float* inv_in   = (float*)(csr_eid + (size_t)CAP * N);  // N
    float* inv_out  = inv_in + N;              // N
    float* inv_mean = inv_out + N;             // N
    float* bcoef    = inv_mean + N;            // N
    float* efa      = bcoef + N;               // 32N (densely written by gather_e4_k)
    u16* h0   = (u16*)(efa + (size_t)32 * N);  // [N,128] bf16 (x inv_out)
    u16* aggA = h0 + (size_t)128 * N;          // [N,128] bf16 (x inv_in)
    u16* h1   = aggA + (size_t)128 * N;        // [N,192] bf16 (x inv_out)
    u16* aggB = h1 + (size_t)192 * N;          // [N,192] bf16 (x inv_in)
    u16* Wp0  = aggB + (size_t)192 * N;        // 128*192
    u16* Wp1  = Wp0 + 128 * 192;               // 192*192
    u16* Wp2  = Wp1 + 192 * 192;               // 192*192
    // partition buffer (9.6 MB u64) aliases h1 (19.2 MB): consumed by fill_k long
    // before mfma_gemm_k writes h1. h1 offset is a 16B multiple -> u64-aligned.
    u64* part = (u64*)h1;

    hipMemsetAsync(d_ws, 0, (size_t)(N + NBKT_PAD) * sizeof(int), stream);

    const int GB32 = (N + 31) / 32;   // small-GEMM grid
    const int GB16 = N / 16;          // mfma grid (3125, exact)
    const int GW4  = (N + 3) / 4;     // wave-per-node gather grid (12500)

    // weight packing (tiny, every launch)
    pack_w_k<128><<<dim3(12), dim3(256), 0, stream>>>(Wc0, Wp0);
    pack_w_k<192><<<dim3(18), dim3(256), 0, stream>>>(Wc1, Wp1);
    pack_w_k<192><<<dim3(18), dim3(256), 0, stream>>>(Wl0, Wp2);

    // two-pass bucketed build: partition by dst bucket, then L2-local CSR fill
    partition_k<<<dim3((E + CHUNK - 1) / CHUNK), dim3(256), 0, stream>>>(
        src, dst, dout, bktc, part, E);
    fill_k<<<dim3(NBKT), dim3(256), 0, stream>>>(part, bktc, csr_src, csr_eid, din, N);
    make_inv_k<<<dim3((N + 255) / 256), dim3(256), 0, stream>>>(din, dout, inv_in, inv_out,
                                                                inv_mean, bcoef, N);

    // edge aggregation: efa = segment_sum(edge_feats, dst)  (fp32 pull-gather)
    gather_e4_k<<<dim3(GW4), dim3(256), 0, stream>>>(edge_feats, csr_eid, din, efa);

    // h0[:,0:32] = bf16( relu((efa*inv_mean)@We + bcoef*be) * inv_out )
    gemm_tile_k<32, 32, true, true><<<dim3(GB32), dim3(256), 0, stream>>>(
        efa, 32, We, be, inv_mean, bcoef, inv_out, h0, 128, N);
    // h0[:,32:128] = bf16( relu(node_feats@Wn + bn) * inv_out )
    gemm_tile_k<64, 96, false, false><<<dim3(GB32), dim3(256), 0, stream>>>(
        node_feats, 64, Wn, bn, nullptr, nullptr, inv_out, h0 + 32, 128, N);

    // conv0: bf16 gather h0 -> aggA (x inv_in), MFMA GEMM 128->192 -> h1 (x inv_out)
    gather_b2_k<128, 2><<<dim3(GW4), dim3(256), 0, stream>>>(h0, csr_src, din, inv_in, aggA);
    mfma_gemm_k<128><<<dim3(GB16), dim3(256), 0, stream>>>(aggA, Wp0, bc0, inv_out, h1, N);

    // conv1: bf16 gather h1 -> aggB (x inv_in), fused MFMA (conv1 + linear + head) -> out
    gather_b2_k<192, 4><<<dim3(GW4), dim3(256), 0, stream>>>(h1, csr_src, din, inv_in, aggB);
    mfma_fused_k<<<dim3(GB16), dim3(256), 0, stream>>>(aggB, Wp1, bc1, Wp2, bl0, Wo, bo,
                                                       out, N);
}

// Round 5
// 428.705 us; speedup vs baseline: 1.0635x; 1.0020x over previous
//
#include <hip/hip_runtime.h>

#define NN 50000
#define NE 800000
#define CAP 64          // padded CSR slots per node (max deg_in ~40 for Poisson(16))

// ---- bucketed build parameters ----
#define NPB 128         // nodes per bucket (dst >> 7)
#define NBKT 391        // ceil(NN / NPB)
#define NBKT_PAD 512
#define BCAP 3072       // partition slots per bucket (mean 2048, sigma ~45 -> 22 sigma margin)
#define CHUNK 4096      // edges per partition block

typedef unsigned short u16;
typedef unsigned int u32;
typedef unsigned long long u64;
typedef __attribute__((ext_vector_type(8))) short bf8_t;   // 8 x bf16 (4 VGPRs)
typedef __attribute__((ext_vector_type(4))) float f4_t;    // 4 x f32 acc

__device__ __forceinline__ u16 f2b(float f) {              // RNE fp32 -> bf16
    unsigned u = __float_as_uint(f);
    unsigned r = u + 0x7FFF + ((u >> 16) & 1);
    return (u16)(r >> 16);
}

// ---------------- pass A: LDS-staged partition of edges into dst-buckets ----------------
// Packs {eid:32 | dst:16 | src:16} into u64; copy-out is bucket-contiguous bursts so HBM
// lines fill fully. Also builds deg_out histogram.
__global__ __launch_bounds__(256) void partition_k(
    const int* __restrict__ src, const int* __restrict__ dst,
    int* __restrict__ deg_out, int* __restrict__ bktc,
    u64* __restrict__ part, int E) {
    __shared__ unsigned cnt[NBKT_PAD];
    __shared__ unsigned base[NBKT_PAD];
    __shared__ unsigned cur[NBKT_PAD];
    __shared__ unsigned gbase[NBKT_PAD];
    __shared__ unsigned wtot[4];
    __shared__ u64 staged[CHUNK];

    const int tid = threadIdx.x;
    const int lane = tid & 63;
    const int wid = tid >> 6;
    const int e0 = blockIdx.x * CHUNK;
    const int n = min(CHUNK, E - e0);

    for (int i = tid; i < NBKT_PAD; i += 256) cnt[i] = 0;
    __syncthreads();

    // histogram buckets for this chunk
    for (int i = tid; i < n; i += 256) {
        int d = dst[e0 + i];
        atomicAdd(&cnt[d >> 7], 1u);
    }
    __syncthreads();

    // exclusive scan cnt[0..511] -> base (pairs per thread + shfl wave scan)
    {
        unsigned a = cnt[2 * tid];
        unsigned b = cnt[2 * tid + 1];
        unsigned ps = a + b;
        unsigned inc = ps;
#pragma unroll
        for (int d = 1; d < 64; d <<= 1) {
            unsigned v = __shfl_up(inc, d);
            if (lane >= d) inc += v;
        }
        if (lane == 63) wtot[wid] = inc;
        __syncthreads();
        unsigned wb = 0;
#pragma unroll
        for (int k = 0; k < 4; ++k) wb += (k < wid) ? wtot[k] : 0;
        unsigned eb = wb + inc - ps;        // exclusive base of pair slot 2*tid
        base[2 * tid] = eb;
        base[2 * tid + 1] = eb + a;
        cur[2 * tid] = eb;
        cur[2 * tid + 1] = eb + a;
    }
    __syncthreads();

    // scatter into LDS staging, bucket-sorted; deg_out histogram on the side
    for (int i = tid; i < n; i += 256) {
        int e = e0 + i;
        int d = dst[e];
        int s = src[e];
        atomicAdd(deg_out + s, 1);
        unsigned p = atomicAdd(&cur[d >> 7], 1u);
        staged[p] = ((u64)(unsigned)e << 32) | (((u32)d << 16) | (u32)s);
    }
    __syncthreads();

    // reserve global space per bucket
    for (int b = tid; b < NBKT; b += 256) {
        unsigned c = cur[b] - base[b];
        if (c) gbase[b] = (unsigned)atomicAdd(&bktc[b], (int)c);
    }
    __syncthreads();

    // copy out: consecutive i within a bucket -> consecutive global slots (bursts)
    for (int i = tid; i < n; i += 256) {
        u64 v = staged[i];
        int b = (int)((v >> 16) & 0xffffu) >> 7;
        unsigned idx = gbase[b] + ((unsigned)i - base[b]);
        if (idx < BCAP) part[(size_t)b * BCAP + idx] = v;
    }
}

// ---------------- pass B: per-bucket CSR fill + degree-derived scalars ----------------
// One block per bucket; writes parallel src/eid CSRs; LDS cursors give deg_in free.
// Zero-pads csr_eid to the 32-slot batch boundary so gather_eh_k can issue
// UNCONDITIONAL batched loads (pad slots hit the cached eh row 0, adds are masked).
// Tail also computes inv_in/inv_out/inv_mean/bcoef (was make_inv_k).
__global__ __launch_bounds__(256) void fill_k(
    const u64* __restrict__ part, const int* __restrict__ bktc,
    const int* __restrict__ deg_out,
    int* __restrict__ csr_src, int* __restrict__ csr_eid,
    int* __restrict__ din,
    float* __restrict__ inv_in, float* __restrict__ inv_out,
    float* __restrict__ inv_mean, float* __restrict__ bcoef, int n) {
    __shared__ unsigned cur[NPB];
    const int tid = threadIdx.x;
    const int b = blockIdx.x;
    const int node0 = b << 7;
    if (tid < NPB) cur[tid] = 0;
    __syncthreads();

    const int cnt = min(bktc[b], BCAP);
    const u64* p = part + (size_t)b * BCAP;
    for (int i = tid; i < cnt; i += 256) {
        u64 v = p[i];
        int s = (int)(v & 0xffffu);
        int d = (int)((v >> 16) & 0xffffu);
        int e = (int)(v >> 32);
        unsigned q = atomicAdd(&cur[d & (NPB - 1)], 1u);
        if (q < CAP) {
            csr_src[((size_t)d << 6) + q] = s;
            csr_eid[((size_t)d << 6) + q] = e;
        }
    }
    __syncthreads();
    if (tid < NPB) {
        int node = node0 + tid;
        if (node < n) {
            unsigned cq = min(cur[tid], (unsigned)CAP);
            din[node] = (int)cq;
            int end = (cq <= 32u) ? 32 : 64;
            for (int q = (int)cq; q < end; ++q)
                csr_eid[((size_t)node << 6) + q] = 0;
            float di = fmaxf((float)cq, 1.0f);
            float dq = fmaxf((float)deg_out[node], 1.0f);
            inv_in[node]   = 1.0f / sqrtf(di);
            inv_out[node]  = 1.0f / sqrtf(dq);
            inv_mean[node] = 1.0f / di;
            bcoef[node]    = (cq > 0u) ? 1.0f : 0.0f;
        }
    }
}

// ---------------- pack We (fp32 [32][32]) into MFMA B-fragment order, bf16 --------------
__global__ void pack_we_k(const float* __restrict__ We, u16* __restrict__ WpE) {
    int idx = threadIdx.x;            // 128 threads: 2 tiles x 64 lanes
    if (idx >= 128) return;
    int l = idx & 63;
    int t = idx >> 6;
    int col = t * 16 + (l & 15);
    int krow = (l >> 4) * 8;
    u16 tmp[8] __attribute__((aligned(16)));
#pragma unroll
    for (int j = 0; j < 8; ++j) tmp[j] = f2b(We[(size_t)(krow + j) * 32 + col]);
    *(uint4*)(WpE + (size_t)idx * 8) = *(const uint4*)tmp;
}

// ---------------- streaming edge MLP: eh = bf16( ef @ We )  (bias added post-mean) ------
// Sequential full-BW read of ef (102.4 MB), MFMA 16x16x32, LDS-staged coalesced store.
__global__ __launch_bounds__(256) void edge_mlp_k(
    const float* __restrict__ ef, const u16* __restrict__ WpE,
    u16* __restrict__ eh, int E) {
    __shared__ u16 sout[4][16 * 32];
    const int tid = threadIdx.x;
    const int lane = tid & 63;
    const int w = tid >> 6;
    const int row0 = (blockIdx.x * 4 + w) * 16;   // E = 12500*64 exact
    const int arow = row0 + (lane & 15);
    const int kbase = (lane >> 4) * 8;

    // A fragment: 8 f32 -> 8 bf16
    const float* ap = ef + (size_t)arow * 32 + kbase;
    float4 a0 = *(const float4*)(ap);
    float4 a1 = *(const float4*)(ap + 4);
    u16 av[8] __attribute__((aligned(16)));
    av[0] = f2b(a0.x); av[1] = f2b(a0.y); av[2] = f2b(a0.z); av[3] = f2b(a0.w);
    av[4] = f2b(a1.x); av[5] = f2b(a1.y); av[6] = f2b(a1.z); av[7] = f2b(a1.w);
    bf8_t af = *(const bf8_t*)av;

    f4_t acc[2];
#pragma unroll
    for (int o = 0; o < 2; ++o) {
        bf8_t bf = *(const bf8_t*)(WpE + (size_t)(o * 64 + lane) * 8);
        acc[o] = __builtin_amdgcn_mfma_f32_16x16x32_bf16(af, bf, (f4_t){0.f,0.f,0.f,0.f},
                                                         0, 0, 0);
    }

    // stage to LDS in row-major u16, then coalesced 16B stores
    const int drow = (lane >> 4) * 4;
    const int dcol = lane & 15;
#pragma unroll
    for (int o = 0; o < 2; ++o)
#pragma unroll
        for (int r = 0; r < 4; ++r)
            sout[w][(drow + r) * 32 + o * 16 + dcol] = f2b(acc[o][r]);
    // same-wave LDS write->read: lockstep wave64, compiler inserts lgkmcnt wait
    uint4 v = *(const uint4*)&sout[w][lane * 8];
    *(uint4*)(eh + (size_t)row0 * 32 + lane * 8) = v;
}

// ---------------- eh gather + EdgeLayer epilogue -> h0[:,0:32] ----------------
// h0_edge[d] = bf16( relu( sum_e eh[e] * inv_mean + be*bcoef ) * inv_out )
// Fixed unconditional 32-slot batch; 4 rows/instr (16 lanes x 4B per 64B bf16 row).
__global__ __launch_bounds__(256) void gather_eh_k(
    const u16* __restrict__ eh, const int* __restrict__ csr_eid,
    const int* __restrict__ deg,
    const float* __restrict__ inv_mean, const float* __restrict__ bcoef,
    const float* __restrict__ inv_out, const float* __restrict__ be,
    u16* __restrict__ h0) {
    const int lane = threadIdx.x & 63;
    const int node = __builtin_amdgcn_readfirstlane(blockIdx.x * 4 + (threadIdx.x >> 6));
    const int beg = node << 6;
    const int cnt = deg[node];
    const int g = lane >> 4;            // row group 0..3
    const int c = lane & 15;            // uint index (2 bf16 cols)

    float ax = 0.0f, ay = 0.0f;
    {
        int eidv[8];
#pragma unroll
        for (int j = 0; j < 8; ++j) eidv[j] = csr_eid[beg + 4 * j + g];
        unsigned uv[8];
#pragma unroll
        for (int j = 0; j < 8; ++j)
            uv[j] = *(const unsigned*)(eh + (size_t)eidv[j] * 32 + 2 * c);
#pragma unroll
        for (int j = 0; j < 8; ++j)
            if (4 * j + g < cnt) {
                ax += __uint_as_float(uv[j] << 16);
                ay += __uint_as_float(uv[j] & 0xffff0000u);
            }
    }
    if (cnt > 32) {                     // rare, wave-uniform
        int eidv[8];
#pragma unroll
        for (int j = 0; j < 8; ++j) eidv[j] = csr_eid[beg + 32 + 4 * j + g];
        unsigned uv[8];
#pragma unroll
        for (int j = 0; j < 8; ++j)
            uv[j] = *(const unsigned*)(eh + (size_t)eidv[j] * 32 + 2 * c);
#pragma unroll
        for (int j = 0; j < 8; ++j)
            if (32 + 4 * j + g < cnt) {
                ax += __uint_as_float(uv[j] << 16);
                ay += __uint_as_float(uv[j] & 0xffff0000u);
            }
    }
    ax += __shfl_down(ax, 16); ay += __shfl_down(ay, 16);
    ax += __shfl_down(ax, 32); ay += __shfl_down(ay, 32);
    if (lane < 16) {
        float im = inv_mean[node];
        float bc = bcoef[node];
        float po = inv_out[node];
        float v0 = fmaxf(ax * im + be[2 * c] * bc, 0.0f) * po;
        float v1 = fmaxf(ay * im + be[2 * c + 1] * bc, 0.0f) * po;
        unsigned o = (unsigned)f2b(v0) | ((unsigned)f2b(v1) << 16);
        *(unsigned*)(h0 + (size_t)node * 128 + 2 * c) = o;
    }
}

// ---------------- bf16 gather, wave-per-node, 16-deep batches ----------------
// agg[d] = bf16( inv_in[d] * sum_e h[src_e] );  h pre-scaled by inv_out.
template <int D, int LPT>
__global__ __launch_bounds__(256) void gather_b2_k(
    const u16* __restrict__ h, const int* __restrict__ csr,
    const int* __restrict__ deg, const float* __restrict__ inv_in,
    u16* __restrict__ agg) {
    constexpr int ACT = D / LPT;
    constexpr int NW = LPT / 2;          // uints per lane-load
    const int lane = threadIdx.x & 63;
    const int node = __builtin_amdgcn_readfirstlane(blockIdx.x * 4 + (threadIdx.x >> 6));
    const int beg = node << 6;
    const int cnt = deg[node];
    const int off = (lane < ACT ? lane : ACT - 1) * LPT;

    float acc[LPT];
#pragma unroll
    for (int j = 0; j < LPT; ++j) acc[j] = 0.0f;

    // ---- 16-deep batches ----
    const int nb = cnt >> 4;
    int idx[16];
    if (nb > 0) {
#pragma unroll
        for (int j = 0; j < 16; ++j) idx[j] = csr[beg + j];
    }
    for (int b = 0; b < nb; ++b) {
        unsigned lv[16][NW];
#pragma unroll
        for (int j = 0; j < 16; ++j) {
            const unsigned* p = (const unsigned*)(h + (size_t)idx[j] * D + off);
            if constexpr (NW == 2) {
                uint2 t = *(const uint2*)p;
                lv[j][0] = t.x; lv[j][1] = t.y;
            } else {
                lv[j][0] = *p;
            }
        }
        int nidx[16];
        const int nbase = beg + (b + 1) * 16;
        if (b + 1 < nb) {
#pragma unroll
            for (int j = 0; j < 16; ++j) nidx[j] = csr[nbase + j];
        }
#pragma unroll
        for (int j = 0; j < 16; ++j)
#pragma unroll
            for (int q = 0; q < NW; ++q) {
                unsigned u = lv[j][q];
                acc[2 * q]     += __uint_as_float(u << 16);
                acc[2 * q + 1] += __uint_as_float(u & 0xffff0000u);
            }
        if (b + 1 < nb) {
#pragma unroll
            for (int j = 0; j < 16; ++j) idx[j] = nidx[j];
        }
    }

    // ---- tail: one 8-deep batch, then scalar ----
    int tb = beg + (nb << 4);
    int rem = cnt & 15;
    if (rem >= 8) {
        int ti[8];
#pragma unroll
        for (int j = 0; j < 8; ++j) ti[j] = csr[tb + j];
        unsigned lv[8][NW];
#pragma unroll
        for (int j = 0; j < 8; ++j) {
            const unsigned* p = (const unsigned*)(h + (size_t)ti[j] * D + off);
            if constexpr (NW == 2) {
                uint2 t = *(const uint2*)p;
                lv[j][0] = t.x; lv[j][1] = t.y;
            } else {
                lv[j][0] = *p;
            }
        }
#pragma unroll
        for (int j = 0; j < 8; ++j)
#pragma unroll
            for (int q = 0; q < NW; ++q) {
                unsigned u = lv[j][q];
                acc[2 * q]     += __uint_as_float(u << 16);
                acc[2 * q + 1] += __uint_as_float(u & 0xffff0000u);
            }
        tb += 8;
        rem -= 8;
    }
    for (int t = 0; t < rem; ++t) {
        const unsigned* p = (const unsigned*)(h + (size_t)csr[tb + t] * D + off);
#pragma unroll
        for (int q = 0; q < NW; ++q) {
            unsigned u = p[q];
            acc[2 * q]     += __uint_as_float(u << 16);
            acc[2 * q + 1] += __uint_as_float(u & 0xffff0000u);
        }
    }

    if (lane < ACT) {
        float sc = inv_in[node];
        unsigned o[NW];
#pragma unroll
        for (int q = 0; q < NW; ++q)
            o[q] = (unsigned)f2b(acc[2 * q] * sc) | ((unsigned)f2b(acc[2 * q + 1] * sc) << 16);
        unsigned* dp = (unsigned*)(agg + (size_t)node * D + off);
        if constexpr (NW == 2) {
            uint2 t; t.x = o[0]; t.y = o[1];
            *(uint2*)dp = t;
        } else {
            *dp = o[0];
        }
    }
}

// ---------------- small tiled GEMM (64->96), bf16 output -------------------
template <int D_IN, int D_OUT, bool SCALE, bool BROW>
__global__ __launch_bounds__(256) void gemm_tile_k(
    const float* __restrict__ in, int in_stride,
    const float* __restrict__ W, const float* __restrict__ bias,
    const float* __restrict__ scale, const float* __restrict__ brow,
    const float* __restrict__ posts,
    u16* __restrict__ out, int out_stride, int n) {
    constexpr int TMW = 8;
    constexpr int ROWS = TMW * 4;
    constexpr int NOUT = (D_OUT + 63) / 64;
    __shared__ float s_in[ROWS * D_IN];

    const int tid = threadIdx.x;
    const int lane = tid & 63;
    const int wave = tid >> 6;
    const int row0 = blockIdx.x * ROWS;

    constexpr int NV = ROWS * D_IN / 4;
    for (int i = tid; i < NV; i += 256) {
        int m = i / (D_IN / 4);
        int kv = i % (D_IN / 4);
        int row = min(row0 + m, n - 1);
        float4 v = *(const float4*)(in + (size_t)row * in_stride + kv * 4);
        if (SCALE) {
            float s = scale[row];
            v.x *= s; v.y *= s; v.z *= s; v.w *= s;
        }
        *(float4*)(s_in + m * D_IN + kv * 4) = v;
    }
    __syncthreads();

    int f[NOUT], ff[NOUT];
    bool fok[NOUT];
    float bv[NOUT];
#pragma unroll
    for (int o = 0; o < NOUT; ++o) {
        f[o] = lane + 64 * o;
        fok[o] = (f[o] < D_OUT);
        ff[o] = fok[o] ? f[o] : 0;
        bv[o] = bias[ff[o]];
    }

    const float* s_my = s_in + wave * TMW * D_IN;

    float acc[NOUT][TMW];
#pragma unroll
    for (int o = 0; o < NOUT; ++o)
#pragma unroll
        for (int m = 0; m < TMW; ++m) acc[o][m] = 0.0f;

    for (int k = 0; k < D_IN; k += 4) {
        float w[4][NOUT];
#pragma unroll
        for (int j = 0; j < 4; ++j)
#pragma unroll
            for (int o = 0; o < NOUT; ++o) w[j][o] = W[(k + j) * D_OUT + ff[o]];
#pragma unroll
        for (int m = 0; m < TMW; ++m) {
            float4 a = *(const float4*)(s_my + m * D_IN + k);
#pragma unroll
            for (int o = 0; o < NOUT; ++o) {
                acc[o][m] = fmaf(a.x, w[0][o], acc[o][m]);
                acc[o][m] = fmaf(a.y, w[1][o], acc[o][m]);
                acc[o][m] = fmaf(a.z, w[2][o], acc[o][m]);
                acc[o][m] = fmaf(a.w, w[3][o], acc[o][m]);
            }
        }
    }

#pragma unroll
    for (int m = 0; m < TMW; ++m) {
        int row = row0 + wave * TMW + m;
        if (row < n) {
            float bc = BROW ? brow[row] : 1.0f;
            float pm = posts[row];
#pragma unroll
            for (int o = 0; o < NOUT; ++o) {
                if (!fok[o]) continue;
                float v = fmaxf(acc[o][m] + bv[o] * bc, 0.0f) * pm;
                out[(size_t)row * out_stride + f[o]] = f2b(v);
            }
        }
    }
}

// ---------------- pack W (fp32 [K][192]) into MFMA B-fragment order, bf16 ---------------
template <int K>
__global__ void pack_w_k(const float* __restrict__ W, u16* __restrict__ Wp) {
    constexpr int KS = K / 32;
    int idx = blockIdx.x * 256 + threadIdx.x;
    if (idx >= 12 * KS * 64) return;
    int l = idx & 63;
    int s = (idx >> 6) % KS;
    int t = (idx >> 6) / KS;
    int col = t * 16 + (l & 15);
    int krow = s * 32 + ((l >> 4) * 8);
    u16 tmp[8] __attribute__((aligned(16)));
#pragma unroll
    for (int j = 0; j < 8; ++j) tmp[j] = f2b(W[(size_t)(krow + j) * 192 + col]);
    *(uint4*)(Wp + (size_t)idx * 8) = *(const uint4*)tmp;
}

// ---------------- MFMA GEMM (conv0): h1 = bf16( relu(A@W + b) * inv_out ) ----------------
template <int K>
__global__ __launch_bounds__(256) void mfma_gemm_k(
    const u16* __restrict__ A, const u16* __restrict__ Wp,
    const float* __restrict__ bias, const float* __restrict__ posts,
    u16* __restrict__ outB, int n) {
    constexpr int KS = K / 32;
    const int tid = threadIdx.x;
    const int lane = tid & 63;
    const int w = tid >> 6;
    const int row0 = blockIdx.x * 16;
    const int arow = row0 + (lane & 15);
    const int kbase = (lane >> 4) * 8;

    f4_t acc[3];
#pragma unroll
    for (int o = 0; o < 3; ++o) acc[o] = (f4_t){0.f, 0.f, 0.f, 0.f};

    const u16* ap = A + (size_t)arow * K + kbase;
#pragma unroll
    for (int s = 0; s < KS; ++s) {
        bf8_t af = *(const bf8_t*)(ap + s * 32);
#pragma unroll
        for (int o = 0; o < 3; ++o) {
            int t = w * 3 + o;
            bf8_t bf = *(const bf8_t*)(Wp + (size_t)((t * KS + s) * 64 + lane) * 8);
            acc[o] = __builtin_amdgcn_mfma_f32_16x16x32_bf16(af, bf, acc[o], 0, 0, 0);
        }
    }

    const int drow = row0 + (lane >> 4) * 4;
    const int dcol = lane & 15;
    float pm[4];
#pragma unroll
    for (int r = 0; r < 4; ++r) pm[r] = posts[drow + r];
#pragma unroll
    for (int o = 0; o < 3; ++o) {
        int col = (w * 3 + o) * 16 + dcol;
        float bv = bias[col];
#pragma unroll
        for (int r = 0; r < 4; ++r) {
            float v = fmaxf(acc[o][r] + bv, 0.0f) * pm[r];
            outB[(size_t)(drow + r) * 192 + col] = f2b(v);
        }
    }
}

// ---------------- fused MFMA: conv1 GEMM + linear GEMM + head (192->192->192->2) ---------
__global__ __launch_bounds__(256) void mfma_fused_k(
    const u16* __restrict__ A,  // [n,192] bf16 (inv_in pre-scaled)
    const u16* __restrict__ Wp1, const float* __restrict__ b1,
    const u16* __restrict__ Wp2, const float* __restrict__ b2,
    const float* __restrict__ Wo, const float* __restrict__ bo,
    float* __restrict__ out, int n) {
    constexpr int KS = 6;       // 192/32
    constexpr int S = 200;      // LDS row stride
    __shared__ float sbuf[16 * S];
    __shared__ float s_head[16][17][2];

    const int tid = threadIdx.x;
    const int lane = tid & 63;
    const int w = tid >> 6;
    const int row0 = blockIdx.x * 16;
    const int arow = row0 + (lane & 15);
    const int kbase = (lane >> 4) * 8;
    const int drow = (lane >> 4) * 4;
    const int dcol = lane & 15;

    f4_t acc[3];
#pragma unroll
    for (int o = 0; o < 3; ++o) acc[o] = (f4_t){0.f, 0.f, 0.f, 0.f};

    // ---- GEMM 1: A (global bf16) @ W1 ----
    const u16* ap = A + (size_t)arow * 192 + kbase;
#pragma unroll
    for (int s = 0; s < KS; ++s) {
        bf8_t af = *(const bf8_t*)(ap + s * 32);
#pragma unroll
        for (int o = 0; o < 3; ++o) {
            int t = w * 3 + o;
            bf8_t bf = *(const bf8_t*)(Wp1 + (size_t)((t * KS + s) * 64 + lane) * 8);
            acc[o] = __builtin_amdgcn_mfma_f32_16x16x32_bf16(af, bf, acc[o], 0, 0, 0);
        }
    }

    // h2 = relu(acc + b1) -> LDS (bf16)
    u16* h2 = (u16*)sbuf;
#pragma unroll
    for (int o = 0; o < 3; ++o) {
        int col = (w * 3 + o) * 16 + dcol;
        float bv = b1[col];
#pragma unroll
        for (int r = 0; r < 4; ++r)
            h2[(drow + r) * S + col] = f2b(fmaxf(acc[o][r] + bv, 0.0f));
    }
    __syncthreads();

    // ---- GEMM 2: h2 (LDS bf16) @ W2 ----
#pragma unroll
    for (int o = 0; o < 3; ++o) acc[o] = (f4_t){0.f, 0.f, 0.f, 0.f};
    const u16* hp = h2 + (lane & 15) * S + kbase;
#pragma unroll
    for (int s = 0; s < KS; ++s) {
        bf8_t af = *(const bf8_t*)(hp + s * 32);
#pragma unroll
        for (int o = 0; o < 3; ++o) {
            int t = w * 3 + o;
            bf8_t bf = *(const bf8_t*)(Wp2 + (size_t)((t * KS + s) * 64 + lane) * 8);
            acc[o] = __builtin_amdgcn_mfma_f32_16x16x32_bf16(af, bf, acc[o], 0, 0, 0);
        }
    }
    __syncthreads();  // all h2 reads done before overwriting sbuf as f32

    // h3 = relu(acc + b2) -> LDS (f32)
#pragma unroll
    for (int o = 0; o < 3; ++o) {
        int col = (w * 3 + o) * 16 + dcol;
        float bv = b2[col];
#pragma unroll
        for (int r = 0; r < 4; ++r)
            sbuf[(drow + r) * S + col] = fmaxf(acc[o][r] + bv, 0.0f);
    }
    __syncthreads();

    // ---- head: out = h3 @ Wo + bo ----
    {
        int r = tid >> 4;
        int seg = tid & 15;
        const float* hr = sbuf + r * S + seg * 12;
        const float* wor = Wo + seg * 24;
        float p0 = 0.0f, p1 = 0.0f;
#pragma unroll
        for (int c = 0; c < 12; ++c) {
            float hv = hr[c];
            p0 = fmaf(hv, wor[c * 2 + 0], p0);
            p1 = fmaf(hv, wor[c * 2 + 1], p1);
        }
        s_head[r][seg][0] = p0;
        s_head[r][seg][1] = p1;
    }
    __syncthreads();
    if (tid < 32) {
        int r = tid >> 1, c = tid & 1;
        float sum = bo[c];
#pragma unroll
        for (int g = 0; g < 16; ++g) sum += s_head[r][g][c];
        int row = row0 + r;
        if (row < n) out[(size_t)row * 2 + c] = sum;
    }
}

extern "C" void kernel_launch(void* const* d_in, const int* in_sizes, int n_in,
                              void* d_out, int out_size, void* d_ws, size_t ws_size,
                              hipStream_t stream) {
    const float* node_feats = (const float*)d_in[0];   // [N,64]
    const float* edge_feats = (const float*)d_in[1];   // [E,32]
    const float* Wn  = (const float*)d_in[2];          // [64,96]
    const float* bn  = (const float*)d_in[3];
    const float* We  = (const float*)d_in[4];          // [32,32]
    const float* be  = (const float*)d_in[5];
    const float* Wc0 = (const float*)d_in[6];          // [128,192]
    const float* bc0 = (const float*)d_in[7];
    const float* Wc1 = (const float*)d_in[8];          // [192,192]
    const float* bc1 = (const float*)d_in[9];
    const float* Wl0 = (const float*)d_in[10];         // [192,192]
    const float* bl0 = (const float*)d_in[11];
    const float* Wo  = (const float*)d_in[12];         // [192,2]
    const float* bo  = (const float*)d_in[13];
    const int* src = (const int*)d_in[14];
    const int* dst = (const int*)d_in[15];
    float* out = (float*)d_out;

    const int N = NN, E = NE;

    // ---- workspace layout (16B-aligned sections) ----
    // zeroed prefix: [deg_out | bktc]  (tiny)
    int* dout      = (int*)d_ws;               // N (zeroed) -> deg_out
    int* bktc      = dout + N;                 // NBKT_PAD (zeroed) -> bucket cursors
    int* din       = bktc + NBKT_PAD;          // N deg_in (written by fill_k)
    int* csr_src   = din + N;                  // CAP*N ints (padded CSR, src ids)
    int* csr_eid   = csr_src + (size_t)CAP * N;// CAP*N ints (padded CSR, edge ids; 0-padded)
    float* inv_in   = (float*)(csr_eid + (size_t)CAP * N);  // N
    float* inv_out  = inv_in + N;              // N
    float* inv_mean = inv_out + N;             // N
    float* bcoef    = inv_mean + N;            // N
    u16* h0   = (u16*)(bcoef + N);             // [N,128] bf16 (x inv_out)
    u16* aggA = h0 + (size_t)128 * N;          // [N,128] bf16 (x inv_in)
    u16* h1   = aggA + (size_t)128 * N;        // [N,192] bf16 (x inv_out)
    u16* aggB = h1 + (size_t)192 * N;          // [N,192] bf16 (x inv_in)
    u16* Wp0  = aggB + (size_t)192 * N;        // 128*192
    u16* Wp1  = Wp0 + 128 * 192;               // 192*192
    u16* Wp2  = Wp1 + 192 * 192;               // 192*192
    u16* WpE  = Wp2 + 192 * 192;               // 2*64*8 = 1024
    u16* eh   = WpE + 1024;                    // [E,32] bf16 (51.2 MB)
    // partition buffer (9.6 MB u64) aliases h1 (19.2 MB): consumed by fill_k long
    // before mfma_gemm_k writes h1. h1 offset is a 16B multiple -> u64-aligned.
    u64* part = (u64*)h1;

    hipMemsetAsync(d_ws, 0, (size_t)(N + NBKT_PAD) * sizeof(int), stream);

    const int GB32 = (N + 31) / 32;   // small-GEMM grid
    const int GB16 = N / 16;          // mfma grid (3125, exact)
    const int GW4  = (N + 3) / 4;     // wave-per-node gather grid (12500)
    const int GEM  = E / 64;          // edge MLP grid (12500, exact)

    // weight packing (tiny, every launch)
    pack_w_k<128><<<dim3(12), dim3(256), 0, stream>>>(Wc0, Wp0);
    pack_w_k<192><<<dim3(18), dim3(256), 0, stream>>>(Wc1, Wp1);
    pack_w_k<192><<<dim3(18), dim3(256), 0, stream>>>(Wl0, Wp2);
    pack_we_k<<<dim3(1), dim3(128), 0, stream>>>(We, WpE);

    // two-pass bucketed build: partition by dst bucket, then L2-local CSR fill (+inv)
    partition_k<<<dim3((E + CHUNK - 1) / CHUNK), dim3(256), 0, stream>>>(
        src, dst, dout, bktc, part, E);
    fill_k<<<dim3(NBKT), dim3(256), 0, stream>>>(part, bktc, dout, csr_src, csr_eid,
                                                 din, inv_in, inv_out, inv_mean, bcoef, N);

    // streaming edge MLP: eh = bf16(ef @ We)  (sequential full-BW pass, MFMA)
    edge_mlp_k<<<dim3(GEM), dim3(256), 0, stream>>>(edge_feats, WpE, eh, E);
    // eh gather + EdgeLayer epilogue -> h0[:,0:32]
    gather_eh_k<<<dim3(GW4), dim3(256), 0, stream>>>(eh, csr_eid, din, inv_mean, bcoef,
                                                     inv_out, be, h0);
    // h0[:,32:128] = bf16( relu(node_feats@Wn + bn) * inv_out )
    gemm_tile_k<64, 96, false, false><<<dim3(GB32), dim3(256), 0, stream>>>(
        node_feats, 64, Wn, bn, nullptr, nullptr, inv_out, h0 + 32, 128, N);

    // conv0: bf16 gather h0 -> aggA (x inv_in), MFMA GEMM 128->192 -> h1 (x inv_out)
    gather_b2_k<128, 2><<<dim3(GW4), dim3(256), 0, stream>>>(h0, csr_src, din, inv_in, aggA);
    mfma_gemm_k<128><<<dim3(GB16), dim3(256), 0, stream>>>(aggA, Wp0, bc0, inv_out, h1, N);

    // conv1: bf16 gather h1 -> aggB (x inv_in), fused MFMA (conv1 + linear + head) -> out
    gather_b2_k<192, 4><<<dim3(GW4), dim3(256), 0, stream>>>(h1, csr_src, din, inv_in, aggB);
    mfma_fused_k<<<dim3(GB16), dim3(256), 0, stream>>>(aggB, Wp1, bc1, Wp2, bl0, Wo, bo,
                                                       out, N);
}